// Round 2
// baseline (280.264 us; speedup 1.0000x reference)
//
#include <hip/hip_runtime.h>
#include <math.h>

#define H 128
typedef unsigned int u32;
typedef unsigned long long u64;
typedef __attribute__((ext_vector_type(8))) short short8;
typedef __attribute__((ext_vector_type(4))) float floatx4;

#define XS_STRIDE 136   // bf16 elems per padded row (128 + 8) -> 272B, 2-way free
#define CS_STRIDE 40    // counts row stride (80B) -> conflict-free b128 reads

#define SCAN_B 64
#define SCAN_T 256

__device__ __forceinline__ float sigmoid_f(float x) {
    return 1.0f / (1.0f + __expf(-x));
}
__device__ __forceinline__ float tanh_f(float x) {
    float t = __expf(-2.0f * fabsf(x));
    float r = (1.0f - t) / (1.0f + t);
    return copysignf(r, x);
}
// f32 -> bf16 bits, round-to-nearest-even (finite inputs)
__device__ __forceinline__ unsigned short f2bf(float x) {
    u32 u = __float_as_uint(x);
    return (unsigned short)((u + 0x7fffu + ((u >> 16) & 1u)) >> 16);
}
__device__ __forceinline__ float bf2f(unsigned short s) {
    return __uint_as_float(((u32)s) << 16);
}
__device__ __forceinline__ float bf_lo32(u32 u) { return __uint_as_float(u << 16); }
__device__ __forceinline__ float bf_hi32(u32 u) { return __uint_as_float(u & 0xffff0000u); }

// ---------------------------------------------------------------------------
// Fused pre-pass: [blocks 0..HB)   h (f32) -> h_b (bf16)
//                 [HB..HB+DB)      deg zero-init
//                 [HB+DB..)        weight prep (W_c fold, embW', Whh swizzle)
// Swizzle (B-frag, 16x16x32): frag[((gtile*4+kc)*64 + l)*8 + i] =
//   W[(gtile*16 + (l&15))][kc*32 + (l>>4)*8 + i]
// ---------------------------------------------------------------------------
__global__ __launch_bounds__(256) void fused_pre_kernel(
    const float* __restrict__ h, unsigned short* __restrict__ h_b, int total8,
    int* __restrict__ deg, int N,
    const float* __restrict__ Wih, const float* __restrict__ Whh,
    const float* __restrict__ Wm,  const float* __restrict__ emb,
    const float* __restrict__ bm,
    unsigned short* __restrict__ Wcs, unsigned short* __restrict__ Whhs,
    unsigned short* __restrict__ embWs, int HB, int DB)
{
    int b = blockIdx.x;
    if (b < HB) {
        int idx = b * 256 + threadIdx.x;
        if (idx >= total8) return;
        const float4* p = (const float4*)(h + (size_t)idx * 8);
        float4 a = p[0], bb = p[1];
        short8 v;
        v[0] = (short)f2bf(a.x);  v[1] = (short)f2bf(a.y);
        v[2] = (short)f2bf(a.z);  v[3] = (short)f2bf(a.w);
        v[4] = (short)f2bf(bb.x); v[5] = (short)f2bf(bb.y);
        v[6] = (short)f2bf(bb.z); v[7] = (short)f2bf(bb.w);
        *(short8*)(h_b + (size_t)idx * 8) = v;
        return;
    }
    if (b < HB + DB) {
        int idx = (b - HB) * 256 + threadIdx.x;
        if (idx < N) deg[idx] = 0;
        return;
    }
    int idx = (b - HB - DB) * 256 + threadIdx.x;
    if (idx < 49152) {
        // ---- W_c[g][k] = sum_c Wih[g][c] * Wm[c][k], f32 acc -> bf16 swizzled
        int g = idx >> 7;          // 0..383
        int k = idx & 127;
        float acc = 0.f;
#pragma unroll 4
        for (int c = 0; c < H; ++c)
            acc += Wih[(size_t)g * H + c] * Wm[(size_t)c * H + k];
        int gate = g >> 7;
        int wi = g & 127;
        int j = wi >> 4, m = wi & 15;
        int kc = k >> 5, q = (k >> 3) & 3, i = k & 7;
        int l = q * 16 + m;
        Wcs[(size_t)(((gate * 8 + j) * 4 + kc) * 64 + l) * 8 + i] = f2bf(acc);
    } else if (idx < 61440) {
        // ---- embW'[t][g] = sum_j (emb[t][j]+bm[j])*Wih[g][j], K=32 frag
        int s = idx - 49152;       // 0..12287
        int i = s & 7;
        int l = (s >> 3) & 63;
        int jb = s >> 9;           // gate*8 + j
        int gate = jb >> 3, jj = jb & 7;
        int q = l >> 4, m = l & 15;
        int t = q * 8 + i;         // edge type (K index)
        unsigned short v = 0;
        if (t < 9) {
            int g = gate * 128 + jj * 16 + m;
            float acc = 0.f;
#pragma unroll 4
            for (int jx = 0; jx < H; ++jx)
                acc += (emb[(size_t)t * H + jx] + bm[jx]) * Wih[(size_t)g * H + jx];
            v = f2bf(acc);
        }
        embWs[s] = v;
    } else if (idx < 67584) {
        // ---- Whh convert + swizzle
        int t2 = idx - 61440;      // 0..6143
        int l  = t2 & 63;
        int kc = (t2 >> 6) & 3;
        int jr = t2 >> 8;
        int m = l & 15, q = l >> 4;
        size_t srco = (size_t)(jr * 16 + m) * H + kc * 32 + q * 8;
        const float4* s0 = (const float4*)(Whh + srco);
        float4 a = s0[0], bb = s0[1];
        short8 v;
        v[0] = (short)f2bf(a.x);  v[1] = (short)f2bf(a.y);
        v[2] = (short)f2bf(a.z);  v[3] = (short)f2bf(a.w);
        v[4] = (short)f2bf(bb.x); v[5] = (short)f2bf(bb.y);
        v[6] = (short)f2bf(bb.z); v[7] = (short)f2bf(bb.w);
        *(short8*)(Whhs + (size_t)t2 * 8) = v;
    }
}

// ---------------------------------------------------------------------------
// CSR build step 1: degree histogram over dst.
// ---------------------------------------------------------------------------
__global__ __launch_bounds__(256) void hist_kernel(
    const int* __restrict__ eidx, int* __restrict__ deg, int E)
{
    int e = blockIdx.x * 256 + threadIdx.x;
    if (e < E) atomicAdd(&deg[eidx[E + e]], 1);
}

// ---------------------------------------------------------------------------
// CSR build step 2a: per-thread chunk sums + per-block totals (parallel).
// ---------------------------------------------------------------------------
__global__ __launch_bounds__(SCAN_T) void scan_part_kernel(
    const int* __restrict__ deg, int* __restrict__ tsum,
    int* __restrict__ bsum, int N, int ipt)
{
    __shared__ int red[SCAN_T];
    int t = threadIdx.x;
    int g = blockIdx.x * SCAN_T + t;
    int s = g * ipt;
    int e = s + ipt < N ? s + ipt : N;
    int sum = 0;
    for (int i = s; i < e; ++i) sum += deg[i];
    tsum[g] = sum;
    red[t] = sum;
    __syncthreads();
    for (int d = SCAN_T / 2; d > 0; d >>= 1) {
        if (t < d) red[t] += red[t + d];
        __syncthreads();
    }
    if (t == 0) bsum[blockIdx.x] = red[0];
}

// ---------------------------------------------------------------------------
// CSR build step 2b (merged): per-block scan of raw bsum + thread sums,
// then write off/pos. Block 0 also writes off[N].
// ---------------------------------------------------------------------------
__global__ __launch_bounds__(SCAN_T) void scan_final_kernel(
    const int* __restrict__ deg, const int* __restrict__ tsum,
    const int* __restrict__ bsum, int* __restrict__ off,
    int* __restrict__ pos, int N, int ipt)
{
    __shared__ int part[SCAN_T];
    __shared__ int bpre[SCAN_B + 1];
    int t = threadIdx.x;
    if (t == 0) {
        int acc = 0;
        for (int b2 = 0; b2 < SCAN_B; ++b2) { bpre[b2] = acc; acc += bsum[b2]; }
        bpre[SCAN_B] = acc;
        if (blockIdx.x == 0) off[N] = acc;
    }
    int g = blockIdx.x * SCAN_T + t;
    part[t] = tsum[g];
    __syncthreads();
    for (int d = 1; d < SCAN_T; d <<= 1) {
        int v = (t >= d) ? part[t - d] : 0;
        __syncthreads();
        part[t] += v;
        __syncthreads();
    }
    int base = bpre[blockIdx.x] + ((t == 0) ? 0 : part[t - 1]);
    int s = g * ipt;
    int e = s + ipt < N ? s + ipt : N;
    for (int i = s; i < e; ++i) {
        off[i] = base;
        pos[i] = base;
        base += deg[i];
    }
}

// ---------------------------------------------------------------------------
// CSR build step 3: scatter edge ids into slots; pack src|type into one int.
// ---------------------------------------------------------------------------
__global__ __launch_bounds__(256) void fill_kernel(
    const int* __restrict__ eidx, const int* __restrict__ etype,
    int* __restrict__ pos, int* __restrict__ packed, int E)
{
    int e = blockIdx.x * 256 + threadIdx.x;
    if (e >= E) return;
    int src = eidx[e];
    int dst = eidx[E + e];
    int t = etype[e];
    t = t < 0 ? 0 : (t > 8 ? 8 : t);
    int p = atomicAdd(&pos[dst], 1);
    packed[p] = src | (t << 24);
}

// ---------------------------------------------------------------------------
// Gather: S[n] = sum_{e: dst=n} h_b[src_e]  (raw h-space sum, f32 acc ->
// bf16), plus packed 7-bit per-type counters -> cnt[n] (u64).
// ---------------------------------------------------------------------------
__global__ __launch_bounds__(256) void gather_kernel(
    const unsigned short* __restrict__ h_b,
    const int* __restrict__ off, const int* __restrict__ packed,
    unsigned short* __restrict__ S_b, u64* __restrict__ cnt, int N)
{
    int n = blockIdx.x * 4 + (threadIdx.x >> 6);
    if (n >= N) return;
    int lane = threadIdx.x & 63;
    int b = off[n], e = off[n + 1];
    float ax = 0.f, ay = 0.f;
    u64 c = 0;
    int i = b;
    for (; i + 4 <= e; i += 4) {
        int u0 = packed[i + 0];
        int u1 = packed[i + 1];
        int u2 = packed[i + 2];
        int u3 = packed[i + 3];
        u32 x0 = *((const u32*)(h_b + (size_t)(u0 & 0xffffff) * H) + lane);
        u32 x1 = *((const u32*)(h_b + (size_t)(u1 & 0xffffff) * H) + lane);
        u32 x2 = *((const u32*)(h_b + (size_t)(u2 & 0xffffff) * H) + lane);
        u32 x3 = *((const u32*)(h_b + (size_t)(u3 & 0xffffff) * H) + lane);
        c += (1ull << (7 * (u0 >> 24))) + (1ull << (7 * (u1 >> 24)))
           + (1ull << (7 * (u2 >> 24))) + (1ull << (7 * (u3 >> 24)));
        ax += bf_lo32(x0) + bf_lo32(x1) + bf_lo32(x2) + bf_lo32(x3);
        ay += bf_hi32(x0) + bf_hi32(x1) + bf_hi32(x2) + bf_hi32(x3);
    }
    for (; i < e; ++i) {
        int u = packed[i];
        u32 x = *((const u32*)(h_b + (size_t)(u & 0xffffff) * H) + lane);
        c += 1ull << (7 * (u >> 24));
        ax += bf_lo32(x);
        ay += bf_hi32(x);
    }
    u32 o = (u32)f2bf(ax) | ((u32)f2bf(ay) << 16);
    *((u32*)(S_b + (size_t)n * H) + lane) = o;
    if (lane == 0) cnt[n] = c;
}

// ---------------------------------------------------------------------------
// Fused GRU (MFMA), 64-node tiles, 4 waves; wave owns 2 j-tiles, loops over
// 4 row-tiles with weight fragments held in registers per (j,kc):
// weight L2 traffic amortized 4x vs per-row-tile reload.
//   gi = S @ W_c^T + counts @ embW' + b_ih
//   gh = h @ Whh^T + b_hh
// ---------------------------------------------------------------------------
__global__ __launch_bounds__(256, 4) void gru_mfma_kernel(
    const unsigned short* __restrict__ S_b, const unsigned short* __restrict__ h_b,
    const unsigned short* __restrict__ Wcs, const unsigned short* __restrict__ Whhs,
    const unsigned short* __restrict__ embWs,
    const float* __restrict__ bih, const float* __restrict__ bhh,
    const u64* __restrict__ cnt,
    const int* __restrict__ numn, float* __restrict__ out, int N)
{
    __shared__ unsigned short xs[64 * XS_STRIDE];    // 17408 B
    __shared__ unsigned short hsb[64 * XS_STRIDE];   // 17408 B
    __shared__ unsigned short cs[64 * CS_STRIDE];    //  5120 B

    int tid = threadIdx.x;
    int node0 = blockIdx.x * 64;

    for (int c = tid; c < 1024; c += 256) {
        int r = c >> 4;
        int k8 = (c & 15) << 3;
        int n = node0 + r;
        int nc = n < N ? n : N - 1;
        *(short8*)(&xs[r * XS_STRIDE + k8]) =
            *(const short8*)(S_b + (size_t)nc * H + k8);
        *(short8*)(&hsb[r * XS_STRIDE + k8]) =
            *(const short8*)(h_b + (size_t)nc * H + k8);
    }
    {
        // counts tile: row r, type-group tg covers t = tg*8 .. tg*8+7 (t<9 live)
        int r = tid >> 2, tg = tid & 3;
        int n = node0 + r;
        u64 cv = cnt[n < N ? n : N - 1];
        short8 v = {0, 0, 0, 0, 0, 0, 0, 0};
        if (tg == 0) {
#pragma unroll
            for (int i = 0; i < 8; ++i)
                v[i] = (short)f2bf((float)((u32)(cv >> (7 * i)) & 127u));
        } else if (tg == 1) {
            v[0] = (short)f2bf((float)((u32)(cv >> 56) & 127u));
        }
        *(short8*)(&cs[r * CS_STRIDE + tg * 8]) = v;
    }
    __syncthreads();

    int lane = tid & 63;
    int wv = tid >> 6;
    int am = lane & 15;
    int aq = lane >> 4;

    int num_nodes = numn[0];
    floatx4 zero = {0.f, 0.f, 0.f, 0.f};

#pragma unroll
    for (int jj = 0; jj < 2; ++jj) {
        int j = wv * 2 + jj;
        floatx4 aIr[4], aHr[4], aIz[4], aHz[4], aIn[4], aHn[4];
        // emb/bias-msg contribution: rank-32 counts MFMA per gate, per row-tile
        {
            short8 er = *(const short8*)(embWs + (size_t)((0 * 8 + j) * 64 + lane) * 8);
            short8 ez = *(const short8*)(embWs + (size_t)((1 * 8 + j) * 64 + lane) * 8);
            short8 en = *(const short8*)(embWs + (size_t)((2 * 8 + j) * 64 + lane) * 8);
#pragma unroll
            for (int rt = 0; rt < 4; ++rt) {
                short8 acn = *(const short8*)(&cs[(rt * 16 + am) * CS_STRIDE + aq * 8]);
                aIr[rt] = __builtin_amdgcn_mfma_f32_16x16x32_bf16(acn, er, zero, 0, 0, 0);
                aIz[rt] = __builtin_amdgcn_mfma_f32_16x16x32_bf16(acn, ez, zero, 0, 0, 0);
                aIn[rt] = __builtin_amdgcn_mfma_f32_16x16x32_bf16(acn, en, zero, 0, 0, 0);
                aHr[rt] = zero; aHz[rt] = zero; aHn[rt] = zero;
            }
        }
#pragma unroll
        for (int kc = 0; kc < 4; ++kc) {
            size_t c_r = (size_t)(((0 * 8 + j) * 4 + kc) * 64 + lane) * 8;
            size_t c_z = (size_t)(((1 * 8 + j) * 4 + kc) * 64 + lane) * 8;
            size_t c_n = (size_t)(((2 * 8 + j) * 4 + kc) * 64 + lane) * 8;
            short8 bir = *(const short8*)(Wcs + c_r);
            short8 bhr = *(const short8*)(Whhs + c_r);
            short8 biz = *(const short8*)(Wcs + c_z);
            short8 bhz = *(const short8*)(Whhs + c_z);
            short8 bin = *(const short8*)(Wcs + c_n);
            short8 bhn = *(const short8*)(Whhs + c_n);
#pragma unroll
            for (int rt = 0; rt < 4; ++rt) {
                int arow = rt * 16 + am;
                short8 axv = *(const short8*)(&xs[arow * XS_STRIDE + kc * 32 + aq * 8]);
                short8 ahv = *(const short8*)(&hsb[arow * XS_STRIDE + kc * 32 + aq * 8]);
                aIr[rt] = __builtin_amdgcn_mfma_f32_16x16x32_bf16(axv, bir, aIr[rt], 0, 0, 0);
                aHr[rt] = __builtin_amdgcn_mfma_f32_16x16x32_bf16(ahv, bhr, aHr[rt], 0, 0, 0);
                aIz[rt] = __builtin_amdgcn_mfma_f32_16x16x32_bf16(axv, biz, aIz[rt], 0, 0, 0);
                aHz[rt] = __builtin_amdgcn_mfma_f32_16x16x32_bf16(ahv, bhz, aHz[rt], 0, 0, 0);
                aIn[rt] = __builtin_amdgcn_mfma_f32_16x16x32_bf16(axv, bin, aIn[rt], 0, 0, 0);
                aHn[rt] = __builtin_amdgcn_mfma_f32_16x16x32_bf16(ahv, bhn, aHn[rt], 0, 0, 0);
            }
        }
        int c = j * 16 + am;
        float b_ir = bih[c],       b_hr = bhh[c];
        float b_iz = bih[128 + c], b_hz = bhh[128 + c];
        float b_in = bih[256 + c], b_hn = bhh[256 + c];
#pragma unroll
        for (int rt = 0; rt < 4; ++rt) {
#pragma unroll
            for (int q = 0; q < 4; ++q) {
                int m = rt * 16 + aq * 4 + q;
                int node = node0 + m;
                if (node < N) {
                    float r  = sigmoid_f(aIr[rt][q] + b_ir + aHr[rt][q] + b_hr);
                    float z  = sigmoid_f(aIz[rt][q] + b_iz + aHz[rt][q] + b_hz);
                    float nv = tanh_f((aIn[rt][q] + b_in) + r * (aHn[rt][q] + b_hn));
                    float hv = bf2f(hsb[m * XS_STRIDE + c]);
                    float o  = (1.0f - z) * nv + z * hv;
                    out[(size_t)node * H + c] = (node < num_nodes) ? o : 0.0f;
                }
            }
        }
    }
}

extern "C" void kernel_launch(void* const* d_in, const int* in_sizes, int n_in,
                              void* d_out, int out_size, void* d_ws, size_t ws_size,
                              hipStream_t stream) {
    const float* h    = (const float*)d_in[0];
    const int*  eidx  = (const int*)d_in[1];
    const int*  etype = (const int*)d_in[2];
    const int*  numn  = (const int*)d_in[3];
    const float* Wm   = (const float*)d_in[4];
    const float* bm   = (const float*)d_in[5];
    const float* emb  = (const float*)d_in[6];
    const float* Wih  = (const float*)d_in[7];
    const float* Whh  = (const float*)d_in[8];
    const float* bih  = (const float*)d_in[9];
    const float* bhh  = (const float*)d_in[10];

    int N = in_sizes[0] / H;
    int E = in_sizes[2];

    // ws layout:
    unsigned short* S_b   = (unsigned short*)d_ws;               // N*H bf16
    unsigned short* h_b   = S_b + (size_t)N * H;                 // N*H bf16
    unsigned short* Wcs   = h_b + (size_t)N * H;                 // 3*H*H (swizzled)
    unsigned short* Whhs  = Wcs + 3 * H * H;                     // 3*H*H (swizzled)
    unsigned short* embWs = Whhs + 3 * H * H;                    // 3*8*64*8 = 12288
    u64* cnt    = (u64*)(embWs + 12288);                         // N (8B-aligned)
    int* deg    = (int*)(cnt + N);                               // N
    int* pos    = deg + N;                                       // N
    int* off    = pos + N;                                       // N+1
    int* packed = off + (N + 1);                                 // E
    int* tsum   = packed + E;                                    // SCAN_B*SCAN_T
    int* bsum   = tsum + SCAN_B * SCAN_T;                        // SCAN_B

    int total8 = N * H / 8;
    int HB = (total8 + 255) / 256;
    int DB = (N + 255) / 256;
    int PB = 264;
    fused_pre_kernel<<<HB + DB + PB, 256, 0, stream>>>(
        h, h_b, total8, deg, N, Wih, Whh, Wm, emb, bm, Wcs, Whhs, embWs, HB, DB);

    hist_kernel<<<(E + 255) / 256, 256, 0, stream>>>(eidx, deg, E);

    int ipt = (N + SCAN_B * SCAN_T - 1) / (SCAN_B * SCAN_T);
    scan_part_kernel<<<SCAN_B, SCAN_T, 0, stream>>>(deg, tsum, bsum, N, ipt);
    scan_final_kernel<<<SCAN_B, SCAN_T, 0, stream>>>(deg, tsum, bsum, off, pos, N, ipt);

    fill_kernel<<<(E + 255) / 256, 256, 0, stream>>>(eidx, etype, pos, packed, E);

    gather_kernel<<<(N + 3) / 4, 256, 0, stream>>>(h_b, off, packed, S_b, cnt, N);

    int nblk64 = (N + 63) / 64;
    gru_mfma_kernel<<<nblk64, 256, 0, stream>>>(S_b, h_b, Wcs, Whhs, embWs,
                                                bih, bhh, cnt, numn, (float*)d_out, N);
}

// Round 3
// 233.522 us; speedup vs baseline: 1.2002x; 1.2002x over previous
//
#include <hip/hip_runtime.h>
#include <math.h>

#define H 128
typedef unsigned int u32;
typedef unsigned long long u64;
typedef __attribute__((ext_vector_type(8))) short short8;
typedef __attribute__((ext_vector_type(4))) float floatx4;

#define XS_STRIDE 136   // bf16 elems per padded row (128 + 8) -> 272B
#define CS_STRIDE 40    // counts row stride (80B) -> conflict-free b128 reads

#define SCAN_B 64
#define SCAN_T 256

__device__ __forceinline__ float sigmoid_f(float x) {
    return 1.0f / (1.0f + __expf(-x));
}
__device__ __forceinline__ float tanh_f(float x) {
    float t = __expf(-2.0f * fabsf(x));
    float r = (1.0f - t) / (1.0f + t);
    return copysignf(r, x);
}
// f32 -> bf16 bits, round-to-nearest-even (finite inputs)
__device__ __forceinline__ unsigned short f2bf(float x) {
    u32 u = __float_as_uint(x);
    return (unsigned short)((u + 0x7fffu + ((u >> 16) & 1u)) >> 16);
}
__device__ __forceinline__ float bf2f(unsigned short s) {
    return __uint_as_float(((u32)s) << 16);
}
__device__ __forceinline__ float bf_lo32(u32 u) { return __uint_as_float(u << 16); }
__device__ __forceinline__ float bf_hi32(u32 u) { return __uint_as_float(u & 0xffff0000u); }

// ---------------------------------------------------------------------------
// Fused pre-pass: [blocks 0..HB)   h (f32) -> h_b (bf16)
//                 [HB..HB+DB)      deg zero-init
//                 [HB+DB..)        weight prep (W_c fold, embW', Whh swizzle)
// Swizzle (B-frag, 16x16x32): frag[((gtile*4+kc)*64 + l)*8 + i] =
//   W[(gtile*16 + (l&15))][kc*32 + (l>>4)*8 + i]
// ---------------------------------------------------------------------------
__global__ __launch_bounds__(256) void fused_pre_kernel(
    const float* __restrict__ h, unsigned short* __restrict__ h_b, int total8,
    int* __restrict__ deg, int N,
    const float* __restrict__ Wih, const float* __restrict__ Whh,
    const float* __restrict__ Wm,  const float* __restrict__ emb,
    const float* __restrict__ bm,
    unsigned short* __restrict__ Wcs, unsigned short* __restrict__ Whhs,
    unsigned short* __restrict__ embWs, int HB, int DB)
{
    int b = blockIdx.x;
    if (b < HB) {
        int idx = b * 256 + threadIdx.x;
        if (idx >= total8) return;
        const float4* p = (const float4*)(h + (size_t)idx * 8);
        float4 a = p[0], bb = p[1];
        short8 v;
        v[0] = (short)f2bf(a.x);  v[1] = (short)f2bf(a.y);
        v[2] = (short)f2bf(a.z);  v[3] = (short)f2bf(a.w);
        v[4] = (short)f2bf(bb.x); v[5] = (short)f2bf(bb.y);
        v[6] = (short)f2bf(bb.z); v[7] = (short)f2bf(bb.w);
        *(short8*)(h_b + (size_t)idx * 8) = v;
        return;
    }
    if (b < HB + DB) {
        int idx = (b - HB) * 256 + threadIdx.x;
        if (idx < N) deg[idx] = 0;
        return;
    }
    int idx = (b - HB - DB) * 256 + threadIdx.x;
    if (idx < 49152) {
        // ---- W_c[g][k] = sum_c Wih[g][c] * Wm[c][k], f32 acc -> bf16 swizzled
        int g = idx >> 7;          // 0..383
        int k = idx & 127;
        float acc = 0.f;
#pragma unroll 4
        for (int c = 0; c < H; ++c)
            acc += Wih[(size_t)g * H + c] * Wm[(size_t)c * H + k];
        int gate = g >> 7;
        int wi = g & 127;
        int j = wi >> 4, m = wi & 15;
        int kc = k >> 5, q = (k >> 3) & 3, i = k & 7;
        int l = q * 16 + m;
        Wcs[(size_t)(((gate * 8 + j) * 4 + kc) * 64 + l) * 8 + i] = f2bf(acc);
    } else if (idx < 61440) {
        // ---- embW'[t][g] = sum_j (emb[t][j]+bm[j])*Wih[g][j], K=32 frag
        int s = idx - 49152;       // 0..12287
        int i = s & 7;
        int l = (s >> 3) & 63;
        int jb = s >> 9;           // gate*8 + j
        int gate = jb >> 3, jj = jb & 7;
        int q = l >> 4, m = l & 15;
        int t = q * 8 + i;         // edge type (K index)
        unsigned short v = 0;
        if (t < 9) {
            int g = gate * 128 + jj * 16 + m;
            float acc = 0.f;
#pragma unroll 4
            for (int jx = 0; jx < H; ++jx)
                acc += (emb[(size_t)t * H + jx] + bm[jx]) * Wih[(size_t)g * H + jx];
            v = f2bf(acc);
        }
        embWs[s] = v;
    } else if (idx < 67584) {
        // ---- Whh convert + swizzle
        int t2 = idx - 61440;      // 0..6143
        int l  = t2 & 63;
        int kc = (t2 >> 6) & 3;
        int jr = t2 >> 8;
        int m = l & 15, q = l >> 4;
        size_t srco = (size_t)(jr * 16 + m) * H + kc * 32 + q * 8;
        const float4* s0 = (const float4*)(Whh + srco);
        float4 a = s0[0], bb = s0[1];
        short8 v;
        v[0] = (short)f2bf(a.x);  v[1] = (short)f2bf(a.y);
        v[2] = (short)f2bf(a.z);  v[3] = (short)f2bf(a.w);
        v[4] = (short)f2bf(bb.x); v[5] = (short)f2bf(bb.y);
        v[6] = (short)f2bf(bb.z); v[7] = (short)f2bf(bb.w);
        *(short8*)(Whhs + (size_t)t2 * 8) = v;
    }
}

// ---------------------------------------------------------------------------
// CSR build step 1: degree histogram over dst.
// ---------------------------------------------------------------------------
__global__ __launch_bounds__(256) void hist_kernel(
    const int* __restrict__ eidx, int* __restrict__ deg, int E)
{
    int e = blockIdx.x * 256 + threadIdx.x;
    if (e < E) atomicAdd(&deg[eidx[E + e]], 1);
}

// ---------------------------------------------------------------------------
// CSR build step 2a: per-thread chunk sums + per-block totals (parallel).
// ---------------------------------------------------------------------------
__global__ __launch_bounds__(SCAN_T) void scan_part_kernel(
    const int* __restrict__ deg, int* __restrict__ tsum,
    int* __restrict__ bsum, int N, int ipt)
{
    __shared__ int red[SCAN_T];
    int t = threadIdx.x;
    int g = blockIdx.x * SCAN_T + t;
    int s = g * ipt;
    int e = s + ipt < N ? s + ipt : N;
    int sum = 0;
    for (int i = s; i < e; ++i) sum += deg[i];
    tsum[g] = sum;
    red[t] = sum;
    __syncthreads();
    for (int d = SCAN_T / 2; d > 0; d >>= 1) {
        if (t < d) red[t] += red[t + d];
        __syncthreads();
    }
    if (t == 0) bsum[blockIdx.x] = red[0];
}

// ---------------------------------------------------------------------------
// CSR build step 2b (merged): per-block scan of raw bsum + thread sums,
// then write off/pos. Block 0 also writes off[N].
// ---------------------------------------------------------------------------
__global__ __launch_bounds__(SCAN_T) void scan_final_kernel(
    const int* __restrict__ deg, const int* __restrict__ tsum,
    const int* __restrict__ bsum, int* __restrict__ off,
    int* __restrict__ pos, int N, int ipt)
{
    __shared__ int part[SCAN_T];
    __shared__ int bpre[SCAN_B + 1];
    int t = threadIdx.x;
    if (t == 0) {
        int acc = 0;
        for (int b2 = 0; b2 < SCAN_B; ++b2) { bpre[b2] = acc; acc += bsum[b2]; }
        bpre[SCAN_B] = acc;
        if (blockIdx.x == 0) off[N] = acc;
    }
    int g = blockIdx.x * SCAN_T + t;
    part[t] = tsum[g];
    __syncthreads();
    for (int d = 1; d < SCAN_T; d <<= 1) {
        int v = (t >= d) ? part[t - d] : 0;
        __syncthreads();
        part[t] += v;
        __syncthreads();
    }
    int base = bpre[blockIdx.x] + ((t == 0) ? 0 : part[t - 1]);
    int s = g * ipt;
    int e = s + ipt < N ? s + ipt : N;
    for (int i = s; i < e; ++i) {
        off[i] = base;
        pos[i] = base;
        base += deg[i];
    }
}

// ---------------------------------------------------------------------------
// CSR build step 3: scatter edge ids into slots; pack src|type into one int.
// ---------------------------------------------------------------------------
__global__ __launch_bounds__(256) void fill_kernel(
    const int* __restrict__ eidx, const int* __restrict__ etype,
    int* __restrict__ pos, int* __restrict__ packed, int E)
{
    int e = blockIdx.x * 256 + threadIdx.x;
    if (e >= E) return;
    int src = eidx[e];
    int dst = eidx[E + e];
    int t = etype[e];
    t = t < 0 ? 0 : (t > 8 ? 8 : t);
    int p = atomicAdd(&pos[dst], 1);
    packed[p] = src | (t << 24);
}

// ---------------------------------------------------------------------------
// Gather: S[n] = sum_{e: dst=n} h_b[src_e]  (raw h-space sum, f32 acc ->
// bf16), plus packed 7-bit per-type counters -> cnt[n] (u64).
// ---------------------------------------------------------------------------
__global__ __launch_bounds__(256) void gather_kernel(
    const unsigned short* __restrict__ h_b,
    const int* __restrict__ off, const int* __restrict__ packed,
    unsigned short* __restrict__ S_b, u64* __restrict__ cnt, int N)
{
    int n = blockIdx.x * 4 + (threadIdx.x >> 6);
    if (n >= N) return;
    int lane = threadIdx.x & 63;
    int b = off[n], e = off[n + 1];
    float ax = 0.f, ay = 0.f;
    u64 c = 0;
    int i = b;
    for (; i + 4 <= e; i += 4) {
        int u0 = packed[i + 0];
        int u1 = packed[i + 1];
        int u2 = packed[i + 2];
        int u3 = packed[i + 3];
        u32 x0 = *((const u32*)(h_b + (size_t)(u0 & 0xffffff) * H) + lane);
        u32 x1 = *((const u32*)(h_b + (size_t)(u1 & 0xffffff) * H) + lane);
        u32 x2 = *((const u32*)(h_b + (size_t)(u2 & 0xffffff) * H) + lane);
        u32 x3 = *((const u32*)(h_b + (size_t)(u3 & 0xffffff) * H) + lane);
        c += (1ull << (7 * (u0 >> 24))) + (1ull << (7 * (u1 >> 24)))
           + (1ull << (7 * (u2 >> 24))) + (1ull << (7 * (u3 >> 24)));
        ax += bf_lo32(x0) + bf_lo32(x1) + bf_lo32(x2) + bf_lo32(x3);
        ay += bf_hi32(x0) + bf_hi32(x1) + bf_hi32(x2) + bf_hi32(x3);
    }
    for (; i < e; ++i) {
        int u = packed[i];
        u32 x = *((const u32*)(h_b + (size_t)(u & 0xffffff) * H) + lane);
        c += 1ull << (7 * (u >> 24));
        ax += bf_lo32(x);
        ay += bf_hi32(x);
    }
    u32 o = (u32)f2bf(ax) | ((u32)f2bf(ay) << 16);
    *((u32*)(S_b + (size_t)n * H) + lane) = o;
    if (lane == 0) cnt[n] = c;
}

// ---------------------------------------------------------------------------
// Fused GRU (MFMA), 64-node tiles, 4 waves; wave owns 2 j-tiles, loops over
// 4 row-tiles. Weight fragments held in registers per (j,kc) and reused for
// all 4 row-tiles (4x L2 amortization vs r1).
// Register-pressure fix vs r2: gi and gh SHARE accumulators for the r/z
// gates (MFMA C-in accumulate), so 16 floatx4 accs (64 VGPR) instead of 24;
// __launch_bounds__(256,2) -> 128 VGPR cap, no scratch spill.
//   aR = counts@embW_r + S@Wc_r^T + h@Whh_r^T
//   aZ = counts@embW_z + S@Wc_z^T + h@Whh_z^T
//   aIn = counts@embW_n + S@Wc_n^T ; aHn = h@Whh_n^T   (kept separate for r*)
// ---------------------------------------------------------------------------
__global__ __launch_bounds__(256, 2) void gru_mfma_kernel(
    const unsigned short* __restrict__ S_b, const unsigned short* __restrict__ h_b,
    const unsigned short* __restrict__ Wcs, const unsigned short* __restrict__ Whhs,
    const unsigned short* __restrict__ embWs,
    const float* __restrict__ bih, const float* __restrict__ bhh,
    const u64* __restrict__ cnt,
    const int* __restrict__ numn, float* __restrict__ out, int N)
{
    __shared__ unsigned short xs[64 * XS_STRIDE];    // 17408 B
    __shared__ unsigned short hsb[64 * XS_STRIDE];   // 17408 B
    __shared__ unsigned short cs[64 * CS_STRIDE];    //  5120 B

    int tid = threadIdx.x;
    int node0 = blockIdx.x * 64;

    for (int c = tid; c < 1024; c += 256) {
        int r = c >> 4;
        int k8 = (c & 15) << 3;
        int n = node0 + r;
        int nc = n < N ? n : N - 1;
        *(short8*)(&xs[r * XS_STRIDE + k8]) =
            *(const short8*)(S_b + (size_t)nc * H + k8);
        *(short8*)(&hsb[r * XS_STRIDE + k8]) =
            *(const short8*)(h_b + (size_t)nc * H + k8);
    }
    {
        // counts tile: row r, type-group tg covers t = tg*8 .. tg*8+7 (t<9 live)
        int r = tid >> 2, tg = tid & 3;
        int n = node0 + r;
        u64 cv = cnt[n < N ? n : N - 1];
        short8 v = {0, 0, 0, 0, 0, 0, 0, 0};
        if (tg == 0) {
#pragma unroll
            for (int i = 0; i < 8; ++i)
                v[i] = (short)f2bf((float)((u32)(cv >> (7 * i)) & 127u));
        } else if (tg == 1) {
            v[0] = (short)f2bf((float)((u32)(cv >> 56) & 127u));
        }
        *(short8*)(&cs[r * CS_STRIDE + tg * 8]) = v;
    }
    __syncthreads();

    int lane = tid & 63;
    int wv = tid >> 6;
    int am = lane & 15;
    int aq = lane >> 4;

    int num_nodes = numn[0];
    floatx4 zero = {0.f, 0.f, 0.f, 0.f};

#pragma unroll
    for (int jj = 0; jj < 2; ++jj) {
        int j = wv * 2 + jj;
        floatx4 aR[4], aZ[4], aIn[4], aHn[4];
        // emb/bias-msg contribution: rank-32 counts MFMA per gate, per row-tile
        {
            short8 er = *(const short8*)(embWs + (size_t)((0 * 8 + j) * 64 + lane) * 8);
            short8 ez = *(const short8*)(embWs + (size_t)((1 * 8 + j) * 64 + lane) * 8);
            short8 en = *(const short8*)(embWs + (size_t)((2 * 8 + j) * 64 + lane) * 8);
#pragma unroll
            for (int rt = 0; rt < 4; ++rt) {
                short8 acn = *(const short8*)(&cs[(rt * 16 + am) * CS_STRIDE + aq * 8]);
                aR[rt]  = __builtin_amdgcn_mfma_f32_16x16x32_bf16(acn, er, zero, 0, 0, 0);
                aZ[rt]  = __builtin_amdgcn_mfma_f32_16x16x32_bf16(acn, ez, zero, 0, 0, 0);
                aIn[rt] = __builtin_amdgcn_mfma_f32_16x16x32_bf16(acn, en, zero, 0, 0, 0);
                aHn[rt] = zero;
            }
        }
#pragma unroll
        for (int kc = 0; kc < 4; ++kc) {
            size_t c_r = (size_t)(((0 * 8 + j) * 4 + kc) * 64 + lane) * 8;
            size_t c_z = (size_t)(((1 * 8 + j) * 4 + kc) * 64 + lane) * 8;
            size_t c_n = (size_t)(((2 * 8 + j) * 4 + kc) * 64 + lane) * 8;
            short8 bir = *(const short8*)(Wcs + c_r);
            short8 bhr = *(const short8*)(Whhs + c_r);
            short8 biz = *(const short8*)(Wcs + c_z);
            short8 bhz = *(const short8*)(Whhs + c_z);
            short8 bin = *(const short8*)(Wcs + c_n);
            short8 bhn = *(const short8*)(Whhs + c_n);
#pragma unroll
            for (int rt = 0; rt < 4; ++rt) {
                int arow = rt * 16 + am;
                short8 axv = *(const short8*)(&xs[arow * XS_STRIDE + kc * 32 + aq * 8]);
                short8 ahv = *(const short8*)(&hsb[arow * XS_STRIDE + kc * 32 + aq * 8]);
                aR[rt]  = __builtin_amdgcn_mfma_f32_16x16x32_bf16(axv, bir, aR[rt], 0, 0, 0);
                aR[rt]  = __builtin_amdgcn_mfma_f32_16x16x32_bf16(ahv, bhr, aR[rt], 0, 0, 0);
                aZ[rt]  = __builtin_amdgcn_mfma_f32_16x16x32_bf16(axv, biz, aZ[rt], 0, 0, 0);
                aZ[rt]  = __builtin_amdgcn_mfma_f32_16x16x32_bf16(ahv, bhz, aZ[rt], 0, 0, 0);
                aIn[rt] = __builtin_amdgcn_mfma_f32_16x16x32_bf16(axv, bin, aIn[rt], 0, 0, 0);
                aHn[rt] = __builtin_amdgcn_mfma_f32_16x16x32_bf16(ahv, bhn, aHn[rt], 0, 0, 0);
            }
        }
        int c = j * 16 + am;
        float b_r = bih[c]       + bhh[c];
        float b_z = bih[128 + c] + bhh[128 + c];
        float b_in = bih[256 + c], b_hn = bhh[256 + c];
#pragma unroll
        for (int rt = 0; rt < 4; ++rt) {
#pragma unroll
            for (int q = 0; q < 4; ++q) {
                int m = rt * 16 + aq * 4 + q;
                int node = node0 + m;
                if (node < N) {
                    float r  = sigmoid_f(aR[rt][q] + b_r);
                    float z  = sigmoid_f(aZ[rt][q] + b_z);
                    float nv = tanh_f((aIn[rt][q] + b_in) + r * (aHn[rt][q] + b_hn));
                    float hv = bf2f(hsb[m * XS_STRIDE + c]);
                    float o  = (1.0f - z) * nv + z * hv;
                    out[(size_t)node * H + c] = (node < num_nodes) ? o : 0.0f;
                }
            }
        }
    }
}

extern "C" void kernel_launch(void* const* d_in, const int* in_sizes, int n_in,
                              void* d_out, int out_size, void* d_ws, size_t ws_size,
                              hipStream_t stream) {
    const float* h    = (const float*)d_in[0];
    const int*  eidx  = (const int*)d_in[1];
    const int*  etype = (const int*)d_in[2];
    const int*  numn  = (const int*)d_in[3];
    const float* Wm   = (const float*)d_in[4];
    const float* bm   = (const float*)d_in[5];
    const float* emb  = (const float*)d_in[6];
    const float* Wih  = (const float*)d_in[7];
    const float* Whh  = (const float*)d_in[8];
    const float* bih  = (const float*)d_in[9];
    const float* bhh  = (const float*)d_in[10];

    int N = in_sizes[0] / H;
    int E = in_sizes[2];

    // ws layout:
    unsigned short* S_b   = (unsigned short*)d_ws;               // N*H bf16
    unsigned short* h_b   = S_b + (size_t)N * H;                 // N*H bf16
    unsigned short* Wcs   = h_b + (size_t)N * H;                 // 3*H*H (swizzled)
    unsigned short* Whhs  = Wcs + 3 * H * H;                     // 3*H*H (swizzled)
    unsigned short* embWs = Whhs + 3 * H * H;                    // 3*8*64*8 = 12288
    u64* cnt    = (u64*)(embWs + 12288);                         // N (8B-aligned)
    int* deg    = (int*)(cnt + N);                               // N
    int* pos    = deg + N;                                       // N
    int* off    = pos + N;                                       // N+1
    int* packed = off + (N + 1);                                 // E
    int* tsum   = packed + E;                                    // SCAN_B*SCAN_T
    int* bsum   = tsum + SCAN_B * SCAN_T;                        // SCAN_B

    int total8 = N * H / 8;
    int HB = (total8 + 255) / 256;
    int DB = (N + 255) / 256;
    int PB = 264;
    fused_pre_kernel<<<HB + DB + PB, 256, 0, stream>>>(
        h, h_b, total8, deg, N, Wih, Whh, Wm, emb, bm, Wcs, Whhs, embWs, HB, DB);

    hist_kernel<<<(E + 255) / 256, 256, 0, stream>>>(eidx, deg, E);

    int ipt = (N + SCAN_B * SCAN_T - 1) / (SCAN_B * SCAN_T);
    scan_part_kernel<<<SCAN_B, SCAN_T, 0, stream>>>(deg, tsum, bsum, N, ipt);
    scan_final_kernel<<<SCAN_B, SCAN_T, 0, stream>>>(deg, tsum, bsum, off, pos, N, ipt);

    fill_kernel<<<(E + 255) / 256, 256, 0, stream>>>(eidx, etype, pos, packed, E);

    gather_kernel<<<(N + 3) / 4, 256, 0, stream>>>(h_b, off, packed, S_b, cnt, N);

    int nblk64 = (N + 63) / 64;
    gru_mfma_kernel<<<nblk64, 256, 0, stream>>>(S_b, h_b, Wcs, Whhs, embWs,
                                                bih, bhh, cnt, numn, (float*)d_out, N);
}

// Round 4
// 225.866 us; speedup vs baseline: 1.2408x; 1.0339x over previous
//
#include <hip/hip_runtime.h>
#include <math.h>

#define H 128
typedef unsigned int u32;
typedef unsigned long long u64;
typedef __attribute__((ext_vector_type(8))) short short8;
typedef __attribute__((ext_vector_type(4))) float floatx4;

#define XS_STRIDE 136   // bf16 elems per padded row (128 + 8) -> 272B
#define CS_STRIDE 40    // counts row stride (80B) -> conflict-free b128 reads

#define SCAN_B 64
#define SCAN_T 256

__device__ __forceinline__ float sigmoid_f(float x) {
    return 1.0f / (1.0f + __expf(-x));
}
__device__ __forceinline__ float tanh_f(float x) {
    float t = __expf(-2.0f * fabsf(x));
    float r = (1.0f - t) / (1.0f + t);
    return copysignf(r, x);
}
// f32 -> bf16 bits, round-to-nearest-even (finite inputs)
__device__ __forceinline__ unsigned short f2bf(float x) {
    u32 u = __float_as_uint(x);
    return (unsigned short)((u + 0x7fffu + ((u >> 16) & 1u)) >> 16);
}
__device__ __forceinline__ float bf2f(unsigned short s) {
    return __uint_as_float(((u32)s) << 16);
}
__device__ __forceinline__ float bf_lo32(u32 u) { return __uint_as_float(u << 16); }
__device__ __forceinline__ float bf_hi32(u32 u) { return __uint_as_float(u & 0xffff0000u); }

// ---------------------------------------------------------------------------
// Fused pre-pass: [blocks 0..HB)   h (f32) -> h_b (bf16)
//                 [HB..HB+DB)      deg zero-init
//                 [HB+DB..)        weight prep (W_c fold, embW', Whh swizzle)
// Swizzle (B-frag, 16x16x32): frag[((gtile*4+kc)*64 + l)*8 + i] =
//   W[(gtile*16 + (l&15))][kc*32 + (l>>4)*8 + i]
// ---------------------------------------------------------------------------
__global__ __launch_bounds__(256) void fused_pre_kernel(
    const float* __restrict__ h, unsigned short* __restrict__ h_b, int total8,
    int* __restrict__ deg, int N,
    const float* __restrict__ Wih, const float* __restrict__ Whh,
    const float* __restrict__ Wm,  const float* __restrict__ emb,
    const float* __restrict__ bm,
    unsigned short* __restrict__ Wcs, unsigned short* __restrict__ Whhs,
    unsigned short* __restrict__ embWs, int HB, int DB)
{
    int b = blockIdx.x;
    if (b < HB) {
        int idx = b * 256 + threadIdx.x;
        if (idx >= total8) return;
        const float4* p = (const float4*)(h + (size_t)idx * 8);
        float4 a = p[0], bb = p[1];
        short8 v;
        v[0] = (short)f2bf(a.x);  v[1] = (short)f2bf(a.y);
        v[2] = (short)f2bf(a.z);  v[3] = (short)f2bf(a.w);
        v[4] = (short)f2bf(bb.x); v[5] = (short)f2bf(bb.y);
        v[6] = (short)f2bf(bb.z); v[7] = (short)f2bf(bb.w);
        *(short8*)(h_b + (size_t)idx * 8) = v;
        return;
    }
    if (b < HB + DB) {
        int idx = (b - HB) * 256 + threadIdx.x;
        if (idx < N) deg[idx] = 0;
        return;
    }
    int idx = (b - HB - DB) * 256 + threadIdx.x;
    if (idx < 49152) {
        // ---- W_c[g][k] = sum_c Wih[g][c] * Wm[c][k], f32 acc -> bf16 swizzled
        int g = idx >> 7;          // 0..383
        int k = idx & 127;
        float acc = 0.f;
#pragma unroll 4
        for (int c = 0; c < H; ++c)
            acc += Wih[(size_t)g * H + c] * Wm[(size_t)c * H + k];
        int gate = g >> 7;
        int wi = g & 127;
        int j = wi >> 4, m = wi & 15;
        int kc = k >> 5, q = (k >> 3) & 3, i = k & 7;
        int l = q * 16 + m;
        Wcs[(size_t)(((gate * 8 + j) * 4 + kc) * 64 + l) * 8 + i] = f2bf(acc);
    } else if (idx < 61440) {
        // ---- embW'[t][g] = sum_j (emb[t][j]+bm[j])*Wih[g][j], K=32 frag
        int s = idx - 49152;       // 0..12287
        int i = s & 7;
        int l = (s >> 3) & 63;
        int jb = s >> 9;           // gate*8 + j
        int gate = jb >> 3, jj = jb & 7;
        int q = l >> 4, m = l & 15;
        int t = q * 8 + i;         // edge type (K index)
        unsigned short v = 0;
        if (t < 9) {
            int g = gate * 128 + jj * 16 + m;
            float acc = 0.f;
#pragma unroll 4
            for (int jx = 0; jx < H; ++jx)
                acc += (emb[(size_t)t * H + jx] + bm[jx]) * Wih[(size_t)g * H + jx];
            v = f2bf(acc);
        }
        embWs[s] = v;
    } else if (idx < 67584) {
        // ---- Whh convert + swizzle
        int t2 = idx - 61440;      // 0..6143
        int l  = t2 & 63;
        int kc = (t2 >> 6) & 3;
        int jr = t2 >> 8;
        int m = l & 15, q = l >> 4;
        size_t srco = (size_t)(jr * 16 + m) * H + kc * 32 + q * 8;
        const float4* s0 = (const float4*)(Whh + srco);
        float4 a = s0[0], bb = s0[1];
        short8 v;
        v[0] = (short)f2bf(a.x);  v[1] = (short)f2bf(a.y);
        v[2] = (short)f2bf(a.z);  v[3] = (short)f2bf(a.w);
        v[4] = (short)f2bf(bb.x); v[5] = (short)f2bf(bb.y);
        v[6] = (short)f2bf(bb.z); v[7] = (short)f2bf(bb.w);
        *(short8*)(Whhs + (size_t)t2 * 8) = v;
    }
}

// ---------------------------------------------------------------------------
// CSR build step 1: degree histogram over dst.
// ---------------------------------------------------------------------------
__global__ __launch_bounds__(256) void hist_kernel(
    const int* __restrict__ eidx, int* __restrict__ deg, int E)
{
    int e = blockIdx.x * 256 + threadIdx.x;
    if (e < E) atomicAdd(&deg[eidx[E + e]], 1);
}

// ---------------------------------------------------------------------------
// CSR build step 2a: per-thread chunk sums + per-block totals (parallel).
// ---------------------------------------------------------------------------
__global__ __launch_bounds__(SCAN_T) void scan_part_kernel(
    const int* __restrict__ deg, int* __restrict__ tsum,
    int* __restrict__ bsum, int N, int ipt)
{
    __shared__ int red[SCAN_T];
    int t = threadIdx.x;
    int g = blockIdx.x * SCAN_T + t;
    int s = g * ipt;
    int e = s + ipt < N ? s + ipt : N;
    int sum = 0;
    for (int i = s; i < e; ++i) sum += deg[i];
    tsum[g] = sum;
    red[t] = sum;
    __syncthreads();
    for (int d = SCAN_T / 2; d > 0; d >>= 1) {
        if (t < d) red[t] += red[t + d];
        __syncthreads();
    }
    if (t == 0) bsum[blockIdx.x] = red[0];
}

// ---------------------------------------------------------------------------
// CSR build step 2b (merged): per-block scan of raw bsum + thread sums,
// then write off/pos. Block 0 also writes off[N].
// ---------------------------------------------------------------------------
__global__ __launch_bounds__(SCAN_T) void scan_final_kernel(
    const int* __restrict__ deg, const int* __restrict__ tsum,
    const int* __restrict__ bsum, int* __restrict__ off,
    int* __restrict__ pos, int N, int ipt)
{
    __shared__ int part[SCAN_T];
    __shared__ int bpre[SCAN_B + 1];
    int t = threadIdx.x;
    if (t == 0) {
        int acc = 0;
        for (int b2 = 0; b2 < SCAN_B; ++b2) { bpre[b2] = acc; acc += bsum[b2]; }
        bpre[SCAN_B] = acc;
        if (blockIdx.x == 0) off[N] = acc;
    }
    int g = blockIdx.x * SCAN_T + t;
    part[t] = tsum[g];
    __syncthreads();
    for (int d = 1; d < SCAN_T; d <<= 1) {
        int v = (t >= d) ? part[t - d] : 0;
        __syncthreads();
        part[t] += v;
        __syncthreads();
    }
    int base = bpre[blockIdx.x] + ((t == 0) ? 0 : part[t - 1]);
    int s = g * ipt;
    int e = s + ipt < N ? s + ipt : N;
    for (int i = s; i < e; ++i) {
        off[i] = base;
        pos[i] = base;
        base += deg[i];
    }
}

// ---------------------------------------------------------------------------
// CSR build step 3: scatter edge ids into slots; pack src|type into one int.
// ---------------------------------------------------------------------------
__global__ __launch_bounds__(256) void fill_kernel(
    const int* __restrict__ eidx, const int* __restrict__ etype,
    int* __restrict__ pos, int* __restrict__ packed, int E)
{
    int e = blockIdx.x * 256 + threadIdx.x;
    if (e >= E) return;
    int src = eidx[e];
    int dst = eidx[E + e];
    int t = etype[e];
    t = t < 0 ? 0 : (t > 8 ? 8 : t);
    int p = atomicAdd(&pos[dst], 1);
    packed[p] = src | (t << 24);
}

// ---------------------------------------------------------------------------
// Gather: S[n] = sum_{e: dst=n} h_b[src_e]  (raw h-space sum, f32 acc ->
// bf16), plus packed 7-bit per-type counters -> cnt[n] (u64).
// 8-wide unroll for deeper memory-level parallelism.
// ---------------------------------------------------------------------------
__global__ __launch_bounds__(256) void gather_kernel(
    const unsigned short* __restrict__ h_b,
    const int* __restrict__ off, const int* __restrict__ packed,
    unsigned short* __restrict__ S_b, u64* __restrict__ cnt, int N)
{
    int n = blockIdx.x * 4 + (threadIdx.x >> 6);
    if (n >= N) return;
    int lane = threadIdx.x & 63;
    int b = off[n], e = off[n + 1];
    float ax = 0.f, ay = 0.f;
    u64 c = 0;
    int i = b;
    for (; i + 8 <= e; i += 8) {
        int u0 = packed[i + 0];
        int u1 = packed[i + 1];
        int u2 = packed[i + 2];
        int u3 = packed[i + 3];
        int u4 = packed[i + 4];
        int u5 = packed[i + 5];
        int u6 = packed[i + 6];
        int u7 = packed[i + 7];
        u32 x0 = *((const u32*)(h_b + (size_t)(u0 & 0xffffff) * H) + lane);
        u32 x1 = *((const u32*)(h_b + (size_t)(u1 & 0xffffff) * H) + lane);
        u32 x2 = *((const u32*)(h_b + (size_t)(u2 & 0xffffff) * H) + lane);
        u32 x3 = *((const u32*)(h_b + (size_t)(u3 & 0xffffff) * H) + lane);
        u32 x4 = *((const u32*)(h_b + (size_t)(u4 & 0xffffff) * H) + lane);
        u32 x5 = *((const u32*)(h_b + (size_t)(u5 & 0xffffff) * H) + lane);
        u32 x6 = *((const u32*)(h_b + (size_t)(u6 & 0xffffff) * H) + lane);
        u32 x7 = *((const u32*)(h_b + (size_t)(u7 & 0xffffff) * H) + lane);
        c += (1ull << (7 * (u0 >> 24))) + (1ull << (7 * (u1 >> 24)))
           + (1ull << (7 * (u2 >> 24))) + (1ull << (7 * (u3 >> 24)))
           + (1ull << (7 * (u4 >> 24))) + (1ull << (7 * (u5 >> 24)))
           + (1ull << (7 * (u6 >> 24))) + (1ull << (7 * (u7 >> 24)));
        ax += bf_lo32(x0) + bf_lo32(x1) + bf_lo32(x2) + bf_lo32(x3)
            + bf_lo32(x4) + bf_lo32(x5) + bf_lo32(x6) + bf_lo32(x7);
        ay += bf_hi32(x0) + bf_hi32(x1) + bf_hi32(x2) + bf_hi32(x3)
            + bf_hi32(x4) + bf_hi32(x5) + bf_hi32(x6) + bf_hi32(x7);
    }
    for (; i + 4 <= e; i += 4) {
        int u0 = packed[i + 0];
        int u1 = packed[i + 1];
        int u2 = packed[i + 2];
        int u3 = packed[i + 3];
        u32 x0 = *((const u32*)(h_b + (size_t)(u0 & 0xffffff) * H) + lane);
        u32 x1 = *((const u32*)(h_b + (size_t)(u1 & 0xffffff) * H) + lane);
        u32 x2 = *((const u32*)(h_b + (size_t)(u2 & 0xffffff) * H) + lane);
        u32 x3 = *((const u32*)(h_b + (size_t)(u3 & 0xffffff) * H) + lane);
        c += (1ull << (7 * (u0 >> 24))) + (1ull << (7 * (u1 >> 24)))
           + (1ull << (7 * (u2 >> 24))) + (1ull << (7 * (u3 >> 24)));
        ax += bf_lo32(x0) + bf_lo32(x1) + bf_lo32(x2) + bf_lo32(x3);
        ay += bf_hi32(x0) + bf_hi32(x1) + bf_hi32(x2) + bf_hi32(x3);
    }
    for (; i < e; ++i) {
        int u = packed[i];
        u32 x = *((const u32*)(h_b + (size_t)(u & 0xffffff) * H) + lane);
        c += 1ull << (7 * (u >> 24));
        ax += bf_lo32(x);
        ay += bf_hi32(x);
    }
    u32 o = (u32)f2bf(ax) | ((u32)f2bf(ay) << 16);
    *((u32*)(S_b + (size_t)n * H) + lane) = o;
    if (lane == 0) cnt[n] = c;
}

// ---------------------------------------------------------------------------
// Fused GRU (MFMA). Block = (64-node tile) x (jhalf of 4 j-tiles); 4 waves,
// each wave owns ONE j-tile and loops 4 row-tiles (accs stay register-
// resident, weights loaded once per (kc)). Grid = 2x node-tiles -> ~6
// blocks/CU for latency hiding; LDS 39.9KB -> 4 resident blocks/CU.
//   aR = counts@embW_r + S@Wc_r^T + h@Whh_r^T    (gate-shared accumulators)
//   aZ = counts@embW_z + S@Wc_z^T + h@Whh_z^T
//   aIn = counts@embW_n + S@Wc_n^T ; aHn = h@Whh_n^T
// ---------------------------------------------------------------------------
__global__ __launch_bounds__(256, 4) void gru_mfma_kernel(
    const unsigned short* __restrict__ S_b, const unsigned short* __restrict__ h_b,
    const unsigned short* __restrict__ Wcs, const unsigned short* __restrict__ Whhs,
    const unsigned short* __restrict__ embWs,
    const float* __restrict__ bih, const float* __restrict__ bhh,
    const u64* __restrict__ cnt,
    const int* __restrict__ numn, float* __restrict__ out, int N)
{
    __shared__ unsigned short xs[64 * XS_STRIDE];    // 17408 B
    __shared__ unsigned short hsb[64 * XS_STRIDE];   // 17408 B
    __shared__ unsigned short cs[64 * CS_STRIDE];    //  5120 B

    int tid = threadIdx.x;
    int bx = blockIdx.x;
    int node0 = (bx >> 1) * 64;
    int jhalf = bx & 1;

    int lane = tid & 63;
    int wv = tid >> 6;
    int j = jhalf * 4 + wv;      // this wave's j-tile (0..7)

    // prefetch emb fragments (independent of staging; completes under barrier)
    short8 er = *(const short8*)(embWs + (size_t)((0 * 8 + j) * 64 + lane) * 8);
    short8 ez = *(const short8*)(embWs + (size_t)((1 * 8 + j) * 64 + lane) * 8);
    short8 en = *(const short8*)(embWs + (size_t)((2 * 8 + j) * 64 + lane) * 8);

    for (int c = tid; c < 1024; c += 256) {
        int r = c >> 4;
        int k8 = (c & 15) << 3;
        int n = node0 + r;
        int nc = n < N ? n : N - 1;
        *(short8*)(&xs[r * XS_STRIDE + k8]) =
            *(const short8*)(S_b + (size_t)nc * H + k8);
        *(short8*)(&hsb[r * XS_STRIDE + k8]) =
            *(const short8*)(h_b + (size_t)nc * H + k8);
    }
    {
        // counts tile: row r, type-group tg covers t = tg*8 .. tg*8+7 (t<9 live)
        int r = tid >> 2, tg = tid & 3;
        int n = node0 + r;
        u64 cv = cnt[n < N ? n : N - 1];
        short8 v = {0, 0, 0, 0, 0, 0, 0, 0};
        if (tg == 0) {
#pragma unroll
            for (int i = 0; i < 8; ++i)
                v[i] = (short)f2bf((float)((u32)(cv >> (7 * i)) & 127u));
        } else if (tg == 1) {
            v[0] = (short)f2bf((float)((u32)(cv >> 56) & 127u));
        }
        *(short8*)(&cs[r * CS_STRIDE + tg * 8]) = v;
    }
    __syncthreads();

    int am = lane & 15;
    int aq = lane >> 4;

    int num_nodes = numn[0];
    floatx4 zero = {0.f, 0.f, 0.f, 0.f};

    floatx4 aR[4], aZ[4], aIn[4], aHn[4];
#pragma unroll
    for (int rt = 0; rt < 4; ++rt) {
        short8 acn = *(const short8*)(&cs[(rt * 16 + am) * CS_STRIDE + aq * 8]);
        aR[rt]  = __builtin_amdgcn_mfma_f32_16x16x32_bf16(acn, er, zero, 0, 0, 0);
        aZ[rt]  = __builtin_amdgcn_mfma_f32_16x16x32_bf16(acn, ez, zero, 0, 0, 0);
        aIn[rt] = __builtin_amdgcn_mfma_f32_16x16x32_bf16(acn, en, zero, 0, 0, 0);
        aHn[rt] = zero;
    }
#pragma unroll
    for (int kc = 0; kc < 4; ++kc) {
        size_t c_r = (size_t)(((0 * 8 + j) * 4 + kc) * 64 + lane) * 8;
        size_t c_z = (size_t)(((1 * 8 + j) * 4 + kc) * 64 + lane) * 8;
        size_t c_n = (size_t)(((2 * 8 + j) * 4 + kc) * 64 + lane) * 8;
        short8 bir = *(const short8*)(Wcs + c_r);
        short8 bhr = *(const short8*)(Whhs + c_r);
        short8 biz = *(const short8*)(Wcs + c_z);
        short8 bhz = *(const short8*)(Whhs + c_z);
        short8 bin = *(const short8*)(Wcs + c_n);
        short8 bhn = *(const short8*)(Whhs + c_n);
#pragma unroll
        for (int rt = 0; rt < 4; ++rt) {
            int arow = rt * 16 + am;
            short8 axv = *(const short8*)(&xs[arow * XS_STRIDE + kc * 32 + aq * 8]);
            short8 ahv = *(const short8*)(&hsb[arow * XS_STRIDE + kc * 32 + aq * 8]);
            aR[rt]  = __builtin_amdgcn_mfma_f32_16x16x32_bf16(axv, bir, aR[rt], 0, 0, 0);
            aR[rt]  = __builtin_amdgcn_mfma_f32_16x16x32_bf16(ahv, bhr, aR[rt], 0, 0, 0);
            aZ[rt]  = __builtin_amdgcn_mfma_f32_16x16x32_bf16(axv, biz, aZ[rt], 0, 0, 0);
            aZ[rt]  = __builtin_amdgcn_mfma_f32_16x16x32_bf16(ahv, bhz, aZ[rt], 0, 0, 0);
            aIn[rt] = __builtin_amdgcn_mfma_f32_16x16x32_bf16(axv, bin, aIn[rt], 0, 0, 0);
            aHn[rt] = __builtin_amdgcn_mfma_f32_16x16x32_bf16(ahv, bhn, aHn[rt], 0, 0, 0);
        }
    }
    int c = j * 16 + am;
    float b_r = bih[c]       + bhh[c];
    float b_z = bih[128 + c] + bhh[128 + c];
    float b_in = bih[256 + c], b_hn = bhh[256 + c];
#pragma unroll
    for (int rt = 0; rt < 4; ++rt) {
#pragma unroll
        for (int q = 0; q < 4; ++q) {
            int m = rt * 16 + aq * 4 + q;
            int node = node0 + m;
            if (node < N) {
                float r  = sigmoid_f(aR[rt][q] + b_r);
                float z  = sigmoid_f(aZ[rt][q] + b_z);
                float nv = tanh_f((aIn[rt][q] + b_in) + r * (aHn[rt][q] + b_hn));
                float hv = bf2f(hsb[m * XS_STRIDE + c]);
                float o  = (1.0f - z) * nv + z * hv;
                out[(size_t)node * H + c] = (node < num_nodes) ? o : 0.0f;
            }
        }
    }
}

extern "C" void kernel_launch(void* const* d_in, const int* in_sizes, int n_in,
                              void* d_out, int out_size, void* d_ws, size_t ws_size,
                              hipStream_t stream) {
    const float* h    = (const float*)d_in[0];
    const int*  eidx  = (const int*)d_in[1];
    const int*  etype = (const int*)d_in[2];
    const int*  numn  = (const int*)d_in[3];
    const float* Wm   = (const float*)d_in[4];
    const float* bm   = (const float*)d_in[5];
    const float* emb  = (const float*)d_in[6];
    const float* Wih  = (const float*)d_in[7];
    const float* Whh  = (const float*)d_in[8];
    const float* bih  = (const float*)d_in[9];
    const float* bhh  = (const float*)d_in[10];

    int N = in_sizes[0] / H;
    int E = in_sizes[2];

    // ws layout:
    unsigned short* S_b   = (unsigned short*)d_ws;               // N*H bf16
    unsigned short* h_b   = S_b + (size_t)N * H;                 // N*H bf16
    unsigned short* Wcs   = h_b + (size_t)N * H;                 // 3*H*H (swizzled)
    unsigned short* Whhs  = Wcs + 3 * H * H;                     // 3*H*H (swizzled)
    unsigned short* embWs = Whhs + 3 * H * H;                    // 3*8*64*8 = 12288
    u64* cnt    = (u64*)(embWs + 12288);                         // N (8B-aligned)
    int* deg    = (int*)(cnt + N);                               // N
    int* pos    = deg + N;                                       // N
    int* off    = pos + N;                                       // N+1
    int* packed = off + (N + 1);                                 // E
    int* tsum   = packed + E;                                    // SCAN_B*SCAN_T
    int* bsum   = tsum + SCAN_B * SCAN_T;                        // SCAN_B

    int total8 = N * H / 8;
    int HB = (total8 + 255) / 256;
    int DB = (N + 255) / 256;
    int PB = 264;
    fused_pre_kernel<<<HB + DB + PB, 256, 0, stream>>>(
        h, h_b, total8, deg, N, Wih, Whh, Wm, emb, bm, Wcs, Whhs, embWs, HB, DB);

    hist_kernel<<<(E + 255) / 256, 256, 0, stream>>>(eidx, deg, E);

    int ipt = (N + SCAN_B * SCAN_T - 1) / (SCAN_B * SCAN_T);
    scan_part_kernel<<<SCAN_B, SCAN_T, 0, stream>>>(deg, tsum, bsum, N, ipt);
    scan_final_kernel<<<SCAN_B, SCAN_T, 0, stream>>>(deg, tsum, bsum, off, pos, N, ipt);

    fill_kernel<<<(E + 255) / 256, 256, 0, stream>>>(eidx, etype, pos, packed, E);

    gather_kernel<<<(N + 3) / 4, 256, 0, stream>>>(h_b, off, packed, S_b, cnt, N);

    int nblk = ((N + 63) / 64) * 2;
    gru_mfma_kernel<<<nblk, 256, 0, stream>>>(S_b, h_b, Wcs, Whhs, embWs,
                                              bih, bhh, cnt, numn, (float*)d_out, N);
}